// Round 4
// baseline (150.549 us; speedup 1.0000x reference)
//
#include <hip/hip_runtime.h>
#include <math.h>

#define DIM 2048          // INPUT_DIM
#define NF 2048           // N_FORMULAS
#define LPF 16            // LITERALS_PER_FORMULA
#define LTOT (NF * LPF)   // 32768
#define BETA 0.4f
#define EPS 1.0f

typedef float f32x4 __attribute__((ext_vector_type(4)));

// ---------------------------------------------------------------------------
// Fused kernel: expansion (the 537 MB write) + per-formula partial reduction.
// grid = (NF/64, ndch), block = 256.
// R4 change vs R3: plain stores instead of __builtin_nontemporal_store.
// Stores are full-line (64 lanes x 16B contiguous = 1KB/instr) so no RFO;
// fillBufferAligned proves regular streaming stores reach 6.6+ TB/s.
// ---------------------------------------------------------------------------
__global__ void fused_expand_reduce(const float* __restrict__ lm,
                                    const float* __restrict__ frm,
                                    f32x4* __restrict__ out0,
                                    f32x4* __restrict__ out1,
                                    float* __restrict__ ws,
                                    int dch) {
    const int t = threadIdx.x;
    const int f = blockIdx.x * 64 + (t >> 2);      // formula this thread serves
    const int d0 = blockIdx.y * dch;

    float sq = 0.0f, l1 = 0.0f, cnt = 0.0f;
    const size_t obase = (size_t)blockIdx.x * 256 + t;   // float4 column index

    #pragma unroll 4
    for (int i = 0; i < dch; ++i) {
        const int d = d0 + i;
        const size_t in_off = ((size_t)d << 11) + f;     // d*NF + f
        float x = lm[in_off];
        float r = frm[in_off];
        float bin = (fabsf(x) > EPS) ? 1.0f : 0.0f;

        const size_t o = ((size_t)d << 13) + obase;      // d*(LTOT/4) + col
        f32x4 v0 = { bin, bin, bin, bin };
        f32x4 v1 = { r, r, r, r };
        out0[o] = v0;
        out1[o] = v1;

        sq  = fmaf(x * x, r, sq);
        l1  = fmaf(fabsf(x), r, l1);
        cnt += r;
    }

    if ((t & 3) == 0) {
        float* w = ws + (size_t)blockIdx.y * 3 * NF;
        w[0 * NF + f] = sq;
        w[1 * NF + f] = l1;
        w[2 * NF + f] = cnt;
    }
}

// ---------------------------------------------------------------------------
// Stage B: per-formula term from chunk partials. grid = NF/256 blocks.
// ---------------------------------------------------------------------------
__global__ void formula_term_kernel(const float* __restrict__ ws,
                                    const float* __restrict__ alpha,
                                    float* __restrict__ ws2,
                                    int ndch) {
    const int f = blockIdx.x * blockDim.x + threadIdx.x;
    float sig = 1.0f / (1.0f + expf(-alpha[0]));
    float w_l2 = (1.0f - sig) * 0.5f;
    float w_l1 = sig;

    float sq = 0.0f, l1 = 0.0f, cnt = 0.0f;
    for (int c = 0; c < ndch; ++c) {
        const float* w = ws + (size_t)c * 3 * NF;
        sq  += w[0 * NF + f];
        l1  += w[1 * NF + f];
        cnt += w[2 * NF + f];
    }
    float l2t = fabsf(sq / cnt - BETA * EPS * EPS);
    float l1t = fabsf(l1 / cnt - BETA * EPS);
    ws2[f] = l2t * w_l2 + l1t * w_l1;
}

// ---------------------------------------------------------------------------
// Stage C: mean over formulas. 1 block, deterministic LDS tree.
// ---------------------------------------------------------------------------
__global__ void final_sum_kernel(const float* __restrict__ ws2,
                                 float* __restrict__ out_scalar) {
    __shared__ float red[256];
    const int t = threadIdx.x;
    float total = 0.0f;
    for (int k = 0; k < NF / 256; ++k)
        total += ws2[t + k * 256];
    red[t] = total;
    __syncthreads();
    for (int s = 128; s > 0; s >>= 1) {
        if (t < s) red[t] += red[t + s];
        __syncthreads();
    }
    if (t == 0) out_scalar[0] = red[0] / (float)NF;
}

extern "C" void kernel_launch(void* const* d_in, const int* in_sizes, int n_in,
                              void* d_out, int out_size, void* d_ws, size_t ws_size,
                              hipStream_t stream) {
    const float* lm    = (const float*)d_in[0];  // learnable_mask [D, F]
    const float* alpha = (const float*)d_in[1];  // elastic_net_alpha [1]
    const float* frm   = (const float*)d_in[2];  // formulas_random_mask [D, F]
    // d_in[3] = formula_id_per_literal (implicit: l // 16)

    float* out = (float*)d_out;
    float* ws  = (float*)d_ws;

    const size_t big = (size_t)DIM * LTOT;       // 67,108,864 per output
    f32x4* out0 = (f32x4*)out;                   // learnable_binary_mask
    f32x4* out1 = (f32x4*)(out + big);           // literals_random_mask
    float* out_scalar = out + 2 * big;           // elastic_net_reg

    // choose d-chunk count to fit ws: need (ndch*3*NF + NF)*4 bytes
    int ndch = 64;
    while (ndch > 1 && ((size_t)ndch * 3 * NF + NF) * 4 > ws_size) ndch >>= 1;
    const int dch = DIM / ndch;
    float* ws2 = ws + (size_t)ndch * 3 * NF;

    dim3 grid(NF / 64, ndch);
    fused_expand_reduce<<<grid, 256, 0, stream>>>(lm, frm, out0, out1, ws, dch);
    formula_term_kernel<<<NF / 256, 256, 0, stream>>>(ws, alpha, ws2, ndch);
    final_sum_kernel<<<1, 256, 0, stream>>>(ws2, out_scalar);
}

// Round 5
// 128.153 us; speedup vs baseline: 1.1748x; 1.1748x over previous
//
#include <hip/hip_runtime.h>
#include <math.h>

#define DIM 2048          // INPUT_DIM
#define NF 2048           // N_FORMULAS
#define LPF 16            // LITERALS_PER_FORMULA
#define LTOT (NF * LPF)   // 32768
#define BETA 0.4f
#define EPS 1.0f
#define NDCH 64           // d-chunks for the reduction
#define DCH (DIM / NDCH)  // 32 rows per chunk

typedef float f32x4 __attribute__((ext_vector_type(4)));

// ---------------------------------------------------------------------------
// Kernel A: per-formula partial reduction + LLC prefetch of both inputs.
// grid = (NF/1024, NDCH), block = 256. Each thread owns 4 consecutive
// formulas (float4 loads, fully coalesced). Reads all 33.5 MB of input ->
// warms the 256 MB Infinity Cache so the expand kernel's reads don't
// interleave HBM reads into its write stream.
// ws layout: [NDCH][3][NF] floats, then ws2[NF].
// ---------------------------------------------------------------------------
__global__ void reduce_prefetch(const float* __restrict__ lm,
                                const float* __restrict__ frm,
                                float* __restrict__ ws) {
    const int f4 = blockIdx.x * 256 + threadIdx.x;   // float4 index in row, 0..511
    const int d0 = blockIdx.y * DCH;

    const f32x4* lm4 = (const f32x4*)lm;
    const f32x4* fr4 = (const f32x4*)frm;

    f32x4 sq = {0.f, 0.f, 0.f, 0.f};
    f32x4 l1 = {0.f, 0.f, 0.f, 0.f};
    f32x4 cnt = {0.f, 0.f, 0.f, 0.f};

    #pragma unroll 4
    for (int i = 0; i < DCH; ++i) {
        const size_t off = ((size_t)(d0 + i) << 9) + f4;   // row stride = 512 f4
        f32x4 x = lm4[off];
        f32x4 r = fr4[off];
        #pragma unroll
        for (int j = 0; j < 4; ++j) {
            sq[j]  = fmaf(x[j] * x[j], r[j], sq[j]);
            l1[j]  = fmaf(fabsf(x[j]), r[j], l1[j]);
            cnt[j] += r[j];
        }
    }

    float* w = ws + (size_t)blockIdx.y * 3 * NF;
    ((f32x4*)(w + 0 * NF))[f4] = sq;
    ((f32x4*)(w + 1 * NF))[f4] = l1;
    ((f32x4*)(w + 2 * NF))[f4] = cnt;
}

// ---------------------------------------------------------------------------
// Kernel B: pure expansion, nontemporal stores (R3's winner minus reduction).
// grid = (NF/64, 64), block = 256. Input loads hit LLC (prefetched by A),
// so HBM sees a nearly pure write stream.
// ---------------------------------------------------------------------------
__global__ void expand_nt(const float* __restrict__ lm,
                          const float* __restrict__ frm,
                          f32x4* __restrict__ out0,
                          f32x4* __restrict__ out1) {
    const int t = threadIdx.x;
    const int f = blockIdx.x * 64 + (t >> 2);
    const int d0 = blockIdx.y * DCH;
    const size_t obase = (size_t)blockIdx.x * 256 + t;   // float4 column index

    #pragma unroll 4
    for (int i = 0; i < DCH; ++i) {
        const int d = d0 + i;
        const size_t in_off = ((size_t)d << 11) + f;     // d*NF + f
        float x = lm[in_off];
        float r = frm[in_off];
        float bin = (fabsf(x) > EPS) ? 1.0f : 0.0f;

        const size_t o = ((size_t)d << 13) + obase;      // d*(LTOT/4) + col
        f32x4 v0 = { bin, bin, bin, bin };
        f32x4 v1 = { r, r, r, r };
        __builtin_nontemporal_store(v0, &out0[o]);
        __builtin_nontemporal_store(v1, &out1[o]);
    }
}

// ---------------------------------------------------------------------------
// Kernel C: per-formula term from chunk partials. grid = NF/256 blocks.
// ---------------------------------------------------------------------------
__global__ void formula_term_kernel(const float* __restrict__ ws,
                                    const float* __restrict__ alpha,
                                    float* __restrict__ ws2) {
    const int f = blockIdx.x * blockDim.x + threadIdx.x;
    float sig = 1.0f / (1.0f + expf(-alpha[0]));
    float w_l2 = (1.0f - sig) * 0.5f;
    float w_l1 = sig;

    float sq = 0.0f, l1 = 0.0f, cnt = 0.0f;
    for (int c = 0; c < NDCH; ++c) {
        const float* w = ws + (size_t)c * 3 * NF;
        sq  += w[0 * NF + f];
        l1  += w[1 * NF + f];
        cnt += w[2 * NF + f];
    }
    float l2t = fabsf(sq / cnt - BETA * EPS * EPS);
    float l1t = fabsf(l1 / cnt - BETA * EPS);
    ws2[f] = l2t * w_l2 + l1t * w_l1;
}

// ---------------------------------------------------------------------------
// Kernel D: mean over formulas. 1 block, deterministic LDS tree.
// ---------------------------------------------------------------------------
__global__ void final_sum_kernel(const float* __restrict__ ws2,
                                 float* __restrict__ out_scalar) {
    __shared__ float red[256];
    const int t = threadIdx.x;
    float total = 0.0f;
    for (int k = 0; k < NF / 256; ++k)
        total += ws2[t + k * 256];
    red[t] = total;
    __syncthreads();
    for (int s = 128; s > 0; s >>= 1) {
        if (t < s) red[t] += red[t + s];
        __syncthreads();
    }
    if (t == 0) out_scalar[0] = red[0] / (float)NF;
}

extern "C" void kernel_launch(void* const* d_in, const int* in_sizes, int n_in,
                              void* d_out, int out_size, void* d_ws, size_t ws_size,
                              hipStream_t stream) {
    const float* lm    = (const float*)d_in[0];  // learnable_mask [D, F]
    const float* alpha = (const float*)d_in[1];  // elastic_net_alpha [1]
    const float* frm   = (const float*)d_in[2];  // formulas_random_mask [D, F]
    // d_in[3] = formula_id_per_literal (implicit: l // 16)

    float* out = (float*)d_out;
    float* ws  = (float*)d_ws;   // needs (NDCH*3*NF + NF)*4 = 1.58 MB

    const size_t big = (size_t)DIM * LTOT;       // 67,108,864 per output
    f32x4* out0 = (f32x4*)out;                   // learnable_binary_mask
    f32x4* out1 = (f32x4*)(out + big);           // literals_random_mask
    float* out_scalar = out + 2 * big;           // elastic_net_reg
    float* ws2 = ws + (size_t)NDCH * 3 * NF;

    // A: reduction partials + LLC prefetch of both inputs (reads phase)
    dim3 gridA(NF / 1024, NDCH);
    reduce_prefetch<<<gridA, 256, 0, stream>>>(lm, frm, ws);

    // B: pure nt-write expansion (writes phase; input loads served by LLC)
    dim3 gridB(NF / 64, NDCH);
    expand_nt<<<gridB, 256, 0, stream>>>(lm, frm, out0, out1);

    // C/D: tiny epilogues
    formula_term_kernel<<<NF / 256, 256, 0, stream>>>(ws, alpha, ws2);
    final_sum_kernel<<<1, 256, 0, stream>>>(ws2, out_scalar);
}